// Round 15
// baseline (305.630 us; speedup 1.0000x reference)
//
#include <hip/hip_runtime.h>
#include <hip/hip_bf16.h>
#include <math.h>

#define T_TOK 8192
#define C_DIM 512
#define I_DIM 2048
#define E_NUM 16
#define CAP 640

// ws layout (bytes); peak use ~86 MB (< proven 111 MB)
#define WS_COUNTS 0
#define WS_THR 64
#define WS_INVS 128
#define WS_RW 192
#define WS_LISTS 524480
#define WS_XB 1048768
#define WS_POS 9437376
#define WS_MASKB 9961664
#define WS_H 44040192ull /* bf16 H [E][CAP][I], 41.9 MB */

// out offsets (float elements)
#define OUT_FULL 4194304ull
#define OUT_LOGITS 71303168ull
#define OUT_MASK 71434240ull

#define FULL_F4 16777216     /* full_expert_outputs in float4 units */
#define FILL_CHUNK 21846     /* ceil(FULL_F4 / 768 blocks) */

typedef __attribute__((ext_vector_type(8))) short bf16x8;
typedef __attribute__((ext_vector_type(4))) float f32x4;
typedef __attribute__((ext_vector_type(16))) float f32x16;

__device__ inline unsigned short f2bf(float f) {
  unsigned u = __float_as_uint(f);
  unsigned r = u + 0x7fffu + ((u >> 16) & 1u);
  return (unsigned short)(r >> 16);
}

__device__ inline bf16x8 ldb8(const unsigned short* p) {
  union { uint4 u; bf16x8 v; } w;
  w.u = *(const uint4*)p;
  return w.v;
}

__device__ inline float gelu_f(float x) {
  return 0.5f * x * (1.0f + erff(x * 0.7071067811865476f));
}

// Per-token routing; sim staged to LDS (bank-exact swizzle idx=c*17+e+(c>>3));
// thresholds + sim column norms computed per-block from the LDS copy.
__global__ __launch_bounds__(256) void router_kernel(const float* __restrict__ x,
                                                     const float* __restrict__ sim,
                                                     const float* __restrict__ gates,
                                                     char* __restrict__ wsb,
                                                     float* __restrict__ out) {
  __shared__ float slds[8768];
  __shared__ float part[16][17];
  __shared__ float sthr[E_NUM], sinvs[E_NUM];
  const int tid = threadIdx.x;
  for (int q = tid; q < C_DIM * E_NUM; q += 256)
    slds[(q >> 4) * 17 + (q & 15) + (q >> 7)] = sim[q];

  const int lane = tid & 63;
  const int t = blockIdx.x * 4 + (tid >> 6);

  const float4* xr = (const float4*)(x + (size_t)t * C_DIM + lane * 8);
  float4 v0 = xr[0], v1 = xr[1];
  float xv[8] = {v0.x, v0.y, v0.z, v0.w, v1.x, v1.y, v1.z, v1.w};

  unsigned p[4];
#pragma unroll
  for (int j = 0; j < 4; ++j)
    p[j] = (unsigned)f2bf(xv[2 * j]) | ((unsigned)f2bf(xv[2 * j + 1]) << 16);
  uint4 pk = {p[0], p[1], p[2], p[3]};
  *(uint4*)((unsigned short*)(wsb + WS_XB) + (size_t)t * C_DIM + lane * 8) = pk;

  __syncthreads();

  // per-block norms: e = tid&15, 32-c segment per thread, then 16-way reduce
  {
    const int e = tid & 15, seg = tid >> 4;
    float ps = 0.0f;
    for (int c = seg * 32; c < seg * 32 + 32; ++c) {
      const float v = slds[c * 17 + e + (c >> 3)];
      ps += v * v;
    }
    part[seg][e] = ps;
    __syncthreads();
    if (tid < E_NUM) {
      float ss = 0.0f;
#pragma unroll
      for (int s2 = 0; s2 < 16; ++s2) ss += part[s2][tid];
      sinvs[tid] = 1.0f / fmaxf(sqrtf(ss), 1e-12f);
      sthr[tid] = 1.0f / (1.0f + expf(-gates[tid]));
    }
    __syncthreads();
  }

  float ss = 0.0f;
  float acc[E_NUM];
#pragma unroll
  for (int e = 0; e < E_NUM; ++e) acc[e] = 0.0f;

  const int biL = lane * 137;  // idx(c=8*lane+j, e) = 137*lane + 17*j + e
#pragma unroll
  for (int j = 0; j < 8; ++j) {
    const float xd = xv[j];
    ss += xd * xd;
    const float* sp = slds + biL + 17 * j;
#pragma unroll
    for (int e = 0; e < E_NUM; ++e) acc[e] += xd * sp[e];
  }

#define BRED(v)                 \
  v += __shfl_xor(v, 32);       \
  v += __shfl_xor(v, 16);       \
  v += __shfl_xor(v, 8);        \
  v += __shfl_xor(v, 4);        \
  v += __shfl_xor(v, 2);        \
  v += __shfl_xor(v, 1);

  BRED(ss)
#pragma unroll
  for (int e = 0; e < E_NUM; ++e) { BRED(acc[e]) }

  const float invx = 1.0f / fmaxf(sqrtf(ss), 1e-12f);

  float lg[E_NUM], gt[E_NUM];
  bool mk[E_NUM];
  bool any = false;
#pragma unroll
  for (int e = 0; e < E_NUM; ++e) {
    lg[e] = acc[e] * invx * sinvs[e];
    float d = lg[e] - sthr[e];
    gt[e] = d > 0.0f ? d : 0.0f;
    mk[e] = d > 0.0f;
    any = any || mk[e];
  }
  if (!any) {  // fallback: one-hot argmax (first max, like np.argmax)
    int be = 0;
    float bv = lg[0];
#pragma unroll
    for (int e = 1; e < E_NUM; ++e) {
      if (lg[e] > bv) { bv = lg[e]; be = e; }
    }
#pragma unroll
    for (int e = 0; e < E_NUM; ++e) mk[e] = (e == be);
  }
  float mx = -1e30f;
#pragma unroll
  for (int e = 0; e < E_NUM; ++e) {
    float v = mk[e] ? gt[e] : -1e9f;
    if (v > mx) mx = v;
  }
  float sum = 0.0f;
  float ex[E_NUM];
#pragma unroll
  for (int e = 0; e < E_NUM; ++e) {
    ex[e] = mk[e] ? expf(gt[e] - mx) : 0.0f;
    sum += ex[e];
  }
  const float isum = 1.0f / sum;

  if (lane == 0) {
    float* lg_out = out + OUT_LOGITS + (size_t)t * E_NUM;
    float* mk_out = out + OUT_MASK + (size_t)t * E_NUM;
    float* rw = (float*)(wsb + WS_RW) + (size_t)t * E_NUM;
    unsigned mb = 0;
#pragma unroll
    for (int e = 0; e < E_NUM; ++e) {
      lg_out[e] = lg[e];
      mk_out[e] = mk[e] ? 1.0f : 0.0f;
      rw[e] = ex[e] * isum;
      if (mk[e]) mb |= (1u << e);
    }
    ((unsigned*)(wsb + WS_MASKB))[t] = mb;
  }
}

// Deterministic list build: one block per expert, prefix-scan over 8192 mask bits.
__global__ __launch_bounds__(1024) void build_lists_kernel(char* __restrict__ wsb) {
  const int e = blockIdx.x;
  const int tid = threadIdx.x;
  const unsigned* maskb = (const unsigned*)(wsb + WS_MASKB);
  const int t0 = tid * 8;
  unsigned flags = 0;
#pragma unroll
  for (int j = 0; j < 8; ++j)
    if (maskb[t0 + j] & (1u << e)) flags |= (1u << j);
  const int cnt = __popc(flags);
  const int lane = tid & 63, wid = tid >> 6;
  int v = cnt;
#pragma unroll
  for (int off = 1; off < 64; off <<= 1) {
    int u = __shfl_up(v, off);
    if (lane >= off) v += u;
  }
  __shared__ int wsum[16];
  if (lane == 63) wsum[wid] = v;
  __syncthreads();
  if (tid == 0) {
    int run = 0;
#pragma unroll
    for (int i = 0; i < 16; ++i) {
      int c = wsum[i];
      wsum[i] = run;
      run += c;
    }
    ((int*)(wsb + WS_COUNTS))[e] = run;
  }
  __syncthreads();
  int pos = wsum[wid] + v - cnt;  // exclusive prefix for this thread
  int* lists = (int*)(wsb + WS_LISTS) + e * T_TOK;
  int* posm = (int*)(wsb + WS_POS);
#pragma unroll
  for (int j = 0; j < 8; ++j) {
    const int t = t0 + j;
    int p = -1;
    if (flags & (1u << j)) {
      p = pos++;
      lists[p] = t;
    }
    posm[t * E_NUM + e] = p;
  }
}

// ---- GEMM engine: 512 thr / 8 waves, mfma 32x32x16, fused f32->bf16 transpose
// ---- staging for B, swizzle bks^(i&7)^((i>>3)&7). R15: issue-early prefetch —
// ---- loads issued AFTER the compute barrier, consumed next iteration, so the
// ---- MFMA+ds_read phase covers their latency (m97 issue-early/consume-late).

// Stage 1: H[e][pos][i] = gelu(Xg @ W1col), tile 256x128, K=512. W1 reg-prefetched.
__global__ __launch_bounds__(512, 4) void h_kernel(const float* __restrict__ w1,
                                                   const char* __restrict__ wsb,
                                                   unsigned short* __restrict__ hbuf,
                                                   float* __restrict__ out) {
  const int tid = threadIdx.x;
  // zero-fill chunk of full_expert_outputs (ALL blocks, incl. early-return ones)
  {
    const int bid = (blockIdx.z * 3 + blockIdx.y) * E_NUM + blockIdx.x;  // 0..767
    f32x4* full4 = (f32x4*)(out + OUT_FULL);
    const f32x4 z4 = {0.f, 0.f, 0.f, 0.f};
    const int base = bid * FILL_CHUNK;
#pragma unroll 4
    for (int i = 0; i < 43; ++i) {
      const int idx = base + i * 512 + tid;
      if (idx < FULL_F4 && idx < base + FILL_CHUNK)
        __builtin_nontemporal_store(z4, full4 + idx);
    }
  }

  const int e = blockIdx.x;
  const int ne = min(((const int*)(wsb + WS_COUNTS))[e], CAP);
  const int m0 = blockIdx.y * 256;
  if (m0 >= ne) return;
  const int i0 = blockIdx.z * 128;

  __shared__ unsigned short smem[32768];  // A [0,16384), B [16384,24576); epilogue uses all
  __shared__ int tl[256];
  const int* lists = (const int*)(wsb + WS_LISTS);
  if (tid < 256) tl[tid] = lists[e * T_TOK + min(m0 + tid, ne - 1)];
  __syncthreads();

  const unsigned short* xb = (const unsigned short*)(wsb + WS_XB);
  const unsigned short* sA[4];
  int dA[4];
#pragma unroll
  for (int it = 0; it < 4; ++it) {
    const int q = tid + it * 512, row = q >> 3, gs = q & 7;
    sA[it] = xb + (size_t)tl[row] * C_DIM + gs * 8;
    dA[it] = row * 64 + ((gs ^ (row & 7)) << 3);
  }
  const int kp = tid >> 4, kb = kp * 2, bks = kp >> 2;
  const float* wr0 = w1 + (size_t)e * C_DIM * I_DIM + (size_t)kb * I_DIM + i0;
  const int ccol = (tid & 15) * 4;

  const int lane = tid & 63, wv = tid >> 6;
  const int wm = wv >> 1, wn = wv & 1;
  const int l31 = lane & 31, kh = lane >> 5;
  f32x16 acc[2][2];
  const f32x16 zero16 = {0, 0, 0, 0, 0, 0, 0, 0, 0, 0, 0, 0, 0, 0, 0, 0};
#pragma unroll
  for (int m = 0; m < 2; ++m)
#pragma unroll
    for (int n = 0; n < 2; ++n) acc[m][n] = zero16;

  // prologue: prefetch W (ks=0)
  float4 pw[4];
  pw[0] = *(const float4*)(wr0 + ccol);
  pw[1] = *(const float4*)(wr0 + I_DIM + ccol);
  pw[2] = *(const float4*)(wr0 + ccol + 64);
  pw[3] = *(const float4*)(wr0 + I_DIM + ccol + 64);

  for (int ks = 0; ks < C_DIM / 64; ++ks) {
    __syncthreads();
    // A: load (L3-resident xb) + store
    uint4 av[4];
#pragma unroll
    for (int it = 0; it < 4; ++it) av[it] = *(const uint4*)(sA[it] + ks * 64);
#pragma unroll
    for (int it = 0; it < 4; ++it) *(uint4*)(smem + dA[it]) = av[it];
    // B: convert prefetched W regs -> LDS
#pragma unroll
    for (int j = 0; j < 2; ++j) {
      const int ic = ccol + j * 64;
      const float4 v0 = pw[2 * j];
      const float4 v1 = pw[2 * j + 1];
#pragma unroll
      for (int d = 0; d < 4; ++d) {
        const int i = ic + d;
        const unsigned pk2 = (unsigned)f2bf(((const float*)&v0)[d]) |
                             ((unsigned)f2bf(((const float*)&v1)[d]) << 16);
        *(unsigned*)(smem + 16384 + i * 64 +
                     ((bks ^ (i & 7) ^ ((i >> 3) & 7)) << 3) + (kb & 7)) = pk2;
      }
    }
    __syncthreads();
    // issue next-step W loads; latency covered by the compute below
    if (ks + 1 < C_DIM / 64) {
      const float* wrk = wr0 + (size_t)((ks + 1) * 64) * I_DIM;
      pw[0] = *(const float4*)(wrk + ccol);
      pw[1] = *(const float4*)(wrk + I_DIM + ccol);
      pw[2] = *(const float4*)(wrk + ccol + 64);
      pw[3] = *(const float4*)(wrk + I_DIM + ccol + 64);
    }
#pragma unroll
    for (int s = 0; s < 4; ++s) {
      const int sl = s * 2 + kh;
      bf16x8 af[2], bv[2];
#pragma unroll
      for (int mf = 0; mf < 2; ++mf) {
        const int r = wm * 64 + mf * 32 + l31;
        af[mf] = ldb8(smem + r * 64 + ((sl ^ (r & 7)) << 3));
      }
#pragma unroll
      for (int nf = 0; nf < 2; ++nf) {
        const int i = wn * 64 + nf * 32 + l31;
        bv[nf] = ldb8(smem + 16384 + i * 64 + ((sl ^ (i & 7) ^ ((i >> 3) & 7)) << 3));
      }
#pragma unroll
      for (int mf = 0; mf < 2; ++mf)
#pragma unroll
        for (int nf = 0; nf < 2; ++nf)
          acc[mf][nf] = __builtin_amdgcn_mfma_f32_32x32x16_bf16(af[mf], bv[nf], acc[mf][nf], 0, 0, 0);
    }
  }

  // epilogue: gelu -> bf16 pack [256][128] -> coalesced 16B stores
  __syncthreads();
#pragma unroll
  for (int mf = 0; mf < 2; ++mf)
#pragma unroll
    for (int nf = 0; nf < 2; ++nf) {
      const int col = wn * 64 + nf * 32 + l31;
#pragma unroll
      for (int r = 0; r < 16; ++r) {
        const int row = wm * 64 + mf * 32 + (r & 3) + 8 * (r >> 2) + 4 * kh;
        smem[row * 128 + col] = f2bf(gelu_f(acc[mf][nf][r]));
      }
    }
  __syncthreads();
#pragma unroll
  for (int it = 0; it < 8; ++it) {
    const int q = tid + it * 512, row = q >> 4, slot = q & 15;
    if (m0 + row < CAP)
      *(uint4*)(hbuf + (size_t)(e * CAP + m0 + row) * I_DIM + i0 + slot * 8) =
          *(const uint4*)(smem + row * 128 + slot * 8);
  }
}

// Stage 2: full[t][e][:] = H[e][pos][:] @ W2col, tile 256x64, K=2048.
// R15: both A (H) and W2 fully reg-prefetched one K-step ahead.
__global__ __launch_bounds__(512, 4) void o_kernel(const float* __restrict__ w2,
                                                   const char* __restrict__ wsb,
                                                   const unsigned short* __restrict__ hbuf,
                                                   float* __restrict__ out) {
  const int e = blockIdx.x;
  const int ne = min(((const int*)(wsb + WS_COUNTS))[e], CAP);
  const int m0 = blockIdx.y * 256;
  if (m0 >= ne) return;
  const int n0 = blockIdx.z * 64;

  __shared__ unsigned short smem[20480];  // A [0,16384), B [16384,20480)
  __shared__ int tl[256];
  const int tid = threadIdx.x;
  const int* lists = (const int*)(wsb + WS_LISTS);
  if (tid < 256) tl[tid] = lists[e * T_TOK + min(m0 + tid, ne - 1)];
  __syncthreads();

  const unsigned short* hb = hbuf + (size_t)e * CAP * I_DIM;
  const unsigned short* sA[4];
  int dA[4];
#pragma unroll
  for (int it = 0; it < 4; ++it) {
    const int q = tid + it * 512, row = q >> 3, gs = q & 7;
    sA[it] = hb + (size_t)(m0 + row) * I_DIM + gs * 8;
    dA[it] = row * 64 + ((gs ^ (row & 7)) << 3);
  }
  const int kp = tid >> 4, kb = kp * 2, bks = kp >> 2;
  const float* wr0 = w2 + (size_t)e * I_DIM * C_DIM + (size_t)kb * C_DIM + n0;
  const int ccol = (tid & 15) * 4;  // 0..60 covers 64 cols

  const int lane = tid & 63, wv = tid >> 6;
  const int wm = wv >> 1, wn = wv & 1;
  const int l31 = lane & 31, kh = lane >> 5;
  f32x16 acc[2];
  const f32x16 zero16 = {0, 0, 0, 0, 0, 0, 0, 0, 0, 0, 0, 0, 0, 0, 0, 0};
  acc[0] = zero16;
  acc[1] = zero16;

  // prologue: prefetch A + W (ks=0)
  uint4 pa[4];
  float4 pw0, pw1;
#pragma unroll
  for (int it = 0; it < 4; ++it) pa[it] = *(const uint4*)(sA[it]);
  pw0 = *(const float4*)(wr0 + ccol);
  pw1 = *(const float4*)(wr0 + C_DIM + ccol);

  for (int ks = 0; ks < I_DIM / 64; ++ks) {
    __syncthreads();
    // stage from prefetched regs (wait lands here; latency covered by prev compute)
#pragma unroll
    for (int it = 0; it < 4; ++it) *(uint4*)(smem + dA[it]) = pa[it];
    {
#pragma unroll
      for (int d = 0; d < 4; ++d) {
        const int i = ccol + d;
        const unsigned pk2 = (unsigned)f2bf(((const float*)&pw0)[d]) |
                             ((unsigned)f2bf(((const float*)&pw1)[d]) << 16);
        *(unsigned*)(smem + 16384 + i * 64 +
                     ((bks ^ (i & 7) ^ ((i >> 3) & 7)) << 3) + (kb & 7)) = pk2;
      }
    }
    __syncthreads();
    // issue next-step loads; consumed after the next barrier
    if (ks + 1 < I_DIM / 64) {
      const int kn = (ks + 1) * 64;
#pragma unroll
      for (int it = 0; it < 4; ++it) pa[it] = *(const uint4*)(sA[it] + kn);
      const float* wrk = wr0 + (size_t)kn * C_DIM;
      pw0 = *(const float4*)(wrk + ccol);
      pw1 = *(const float4*)(wrk + C_DIM + ccol);
    }
#pragma unroll
    for (int s = 0; s < 4; ++s) {
      const int sl = s * 2 + kh;
      bf16x8 af[2], bv;
#pragma unroll
      for (int mf = 0; mf < 2; ++mf) {
        const int r = wm * 64 + mf * 32 + l31;
        af[mf] = ldb8(smem + r * 64 + ((sl ^ (r & 7)) << 3));
      }
      {
        const int i = wn * 32 + l31;
        bv = ldb8(smem + 16384 + i * 64 + ((sl ^ (i & 7) ^ ((i >> 3) & 7)) << 3));
      }
#pragma unroll
      for (int mf = 0; mf < 2; ++mf)
        acc[mf] = __builtin_amdgcn_mfma_f32_32x32x16_bf16(af[mf], bv, acc[mf], 0, 0, 0);
    }
  }

  // epilogue: plain stores into full rows
#pragma unroll
  for (int mf = 0; mf < 2; ++mf) {
    const int col = n0 + wn * 32 + l31;
#pragma unroll
    for (int r = 0; r < 16; ++r) {
      const int row = wm * 64 + mf * 32 + (r & 3) + 8 * (r >> 2) + 4 * kh;
      if (m0 + row < ne)
        out[OUT_FULL + ((size_t)tl[row] * E_NUM + e) * C_DIM + col] = acc[mf][r];
    }
  }
}

// final = sum_e rw*full over active experts (inactive rows zero-filled by h).
__global__ __launch_bounds__(256) void scatter_kernel(const char* __restrict__ wsb,
                                                      float* __restrict__ out) {
  const int tid = threadIdx.x;
  const int t = blockIdx.x * 2 + (tid >> 7);
  const int q = tid & 127;
  __shared__ float rws[2][E_NUM];
  __shared__ int ps[2][E_NUM];
  if (tid < 32) {
    const int tt = blockIdx.x * 2 + (tid >> 4);
    rws[tid >> 4][tid & 15] = ((const float*)(wsb + WS_RW))[tt * E_NUM + (tid & 15)];
    ps[tid >> 4][tid & 15] = ((const int*)(wsb + WS_POS))[tt * E_NUM + (tid & 15)];
  }
  __syncthreads();
  const int hw = tid >> 7;
  f32x4 a = {0.f, 0.f, 0.f, 0.f};
  const f32x4* full4 = (const f32x4*)(out + OUT_FULL) + (size_t)t * E_NUM * 128;
#pragma unroll 1
  for (int e = 0; e < E_NUM; ++e) {
    const int p = ps[hw][e];
    if (p >= 0 && p < CAP) {
      const float w = rws[hw][e];
      const f32x4 v = full4[e * 128 + q];
      a += w * v;
    }
  }
  __builtin_nontemporal_store(a, &((f32x4*)out)[(size_t)t * 128 + q]);
}

extern "C" void kernel_launch(void* const* d_in, const int* in_sizes, int n_in,
                              void* d_out, int out_size, void* d_ws, size_t ws_size,
                              hipStream_t stream) {
  const float* x = (const float*)d_in[0];
  const float* sim = (const float*)d_in[1];
  const float* gates = (const float*)d_in[2];
  const float* w1 = (const float*)d_in[3];
  const float* w2 = (const float*)d_in[4];
  float* out = (float*)d_out;
  char* wsb = (char*)d_ws;
  unsigned short* hbuf = (unsigned short*)(wsb + WS_H);

  hipLaunchKernelGGL(router_kernel, dim3(T_TOK / 4), dim3(256), 0, stream, x, sim, gates, wsb, out);
  hipLaunchKernelGGL(build_lists_kernel, dim3(E_NUM), dim3(1024), 0, stream, wsb);
  hipLaunchKernelGGL(h_kernel, dim3(E_NUM, 3, I_DIM / 128), dim3(512), 0, stream, w1, wsb, hbuf, out);
  hipLaunchKernelGGL(o_kernel, dim3(E_NUM, 3, C_DIM / 64), dim3(512), 0, stream, w2, wsb, hbuf, out);
  hipLaunchKernelGGL(scatter_kernel, dim3(T_TOK / 2), dim3(256), 0, stream, wsb, out);
}

// Round 16
// 203.299 us; speedup vs baseline: 1.5034x; 1.5034x over previous
//
#include <hip/hip_runtime.h>
#include <hip/hip_bf16.h>
#include <math.h>

#define T_TOK 8192
#define C_DIM 512
#define I_DIM 2048
#define E_NUM 16
#define CAP 640

// ws layout (bytes); peak use ~86 MB (< proven 111 MB)
#define WS_COUNTS 0
#define WS_THR 64
#define WS_INVS 128
#define WS_RW 192
#define WS_LISTS 524480
#define WS_XB 1048768
#define WS_POS 9437376
#define WS_MASKB 9961664
#define WS_H 44040192ull /* bf16 H [E][CAP][I], 41.9 MB */

// out offsets (float elements)
#define OUT_FULL 4194304ull
#define OUT_LOGITS 71303168ull
#define OUT_MASK 71434240ull

#define FULL_F4 16777216     /* full_expert_outputs in float4 units */
#define FILL_CHUNK 21846     /* ceil(FULL_F4 / 768 blocks) */

typedef __attribute__((ext_vector_type(8))) short bf16x8;
typedef __attribute__((ext_vector_type(4))) float f32x4;
typedef __attribute__((ext_vector_type(16))) float f32x16;

__device__ inline unsigned short f2bf(float f) {
  unsigned u = __float_as_uint(f);
  unsigned r = u + 0x7fffu + ((u >> 16) & 1u);
  return (unsigned short)(r >> 16);
}

__device__ inline bf16x8 ldb8(const unsigned short* p) {
  union { uint4 u; bf16x8 v; } w;
  w.u = *(const uint4*)p;
  return w.v;
}

__device__ inline float gelu_f(float x) {
  return 0.5f * x * (1.0f + erff(x * 0.7071067811865476f));
}

// Per-token routing; sim staged to LDS (bank-exact swizzle idx=c*17+e+(c>>3));
// thresholds + sim column norms computed per-block from the LDS copy.
__global__ __launch_bounds__(256) void router_kernel(const float* __restrict__ x,
                                                     const float* __restrict__ sim,
                                                     const float* __restrict__ gates,
                                                     char* __restrict__ wsb,
                                                     float* __restrict__ out) {
  __shared__ float slds[8768];
  __shared__ float part[16][17];
  __shared__ float sthr[E_NUM], sinvs[E_NUM];
  const int tid = threadIdx.x;
  for (int q = tid; q < C_DIM * E_NUM; q += 256)
    slds[(q >> 4) * 17 + (q & 15) + (q >> 7)] = sim[q];

  const int lane = tid & 63;
  const int t = blockIdx.x * 4 + (tid >> 6);

  const float4* xr = (const float4*)(x + (size_t)t * C_DIM + lane * 8);
  float4 v0 = xr[0], v1 = xr[1];
  float xv[8] = {v0.x, v0.y, v0.z, v0.w, v1.x, v1.y, v1.z, v1.w};

  unsigned p[4];
#pragma unroll
  for (int j = 0; j < 4; ++j)
    p[j] = (unsigned)f2bf(xv[2 * j]) | ((unsigned)f2bf(xv[2 * j + 1]) << 16);
  uint4 pk = {p[0], p[1], p[2], p[3]};
  *(uint4*)((unsigned short*)(wsb + WS_XB) + (size_t)t * C_DIM + lane * 8) = pk;

  __syncthreads();

  // per-block norms: e = tid&15, 32-c segment per thread, then 16-way reduce
  {
    const int e = tid & 15, seg = tid >> 4;
    float ps = 0.0f;
    for (int c = seg * 32; c < seg * 32 + 32; ++c) {
      const float v = slds[c * 17 + e + (c >> 3)];
      ps += v * v;
    }
    part[seg][e] = ps;
    __syncthreads();
    if (tid < E_NUM) {
      float ss = 0.0f;
#pragma unroll
      for (int s2 = 0; s2 < 16; ++s2) ss += part[s2][tid];
      sinvs[tid] = 1.0f / fmaxf(sqrtf(ss), 1e-12f);
      sthr[tid] = 1.0f / (1.0f + expf(-gates[tid]));
    }
    __syncthreads();
  }

  float ss = 0.0f;
  float acc[E_NUM];
#pragma unroll
  for (int e = 0; e < E_NUM; ++e) acc[e] = 0.0f;

  const int biL = lane * 137;  // idx(c=8*lane+j, e) = 137*lane + 17*j + e
#pragma unroll
  for (int j = 0; j < 8; ++j) {
    const float xd = xv[j];
    ss += xd * xd;
    const float* sp = slds + biL + 17 * j;
#pragma unroll
    for (int e = 0; e < E_NUM; ++e) acc[e] += xd * sp[e];
  }

#define BRED(v)                 \
  v += __shfl_xor(v, 32);       \
  v += __shfl_xor(v, 16);       \
  v += __shfl_xor(v, 8);        \
  v += __shfl_xor(v, 4);        \
  v += __shfl_xor(v, 2);        \
  v += __shfl_xor(v, 1);

  BRED(ss)
#pragma unroll
  for (int e = 0; e < E_NUM; ++e) { BRED(acc[e]) }

  const float invx = 1.0f / fmaxf(sqrtf(ss), 1e-12f);

  float lg[E_NUM], gt[E_NUM];
  bool mk[E_NUM];
  bool any = false;
#pragma unroll
  for (int e = 0; e < E_NUM; ++e) {
    lg[e] = acc[e] * invx * sinvs[e];
    float d = lg[e] - sthr[e];
    gt[e] = d > 0.0f ? d : 0.0f;
    mk[e] = d > 0.0f;
    any = any || mk[e];
  }
  if (!any) {  // fallback: one-hot argmax (first max, like np.argmax)
    int be = 0;
    float bv = lg[0];
#pragma unroll
    for (int e = 1; e < E_NUM; ++e) {
      if (lg[e] > bv) { bv = lg[e]; be = e; }
    }
#pragma unroll
    for (int e = 0; e < E_NUM; ++e) mk[e] = (e == be);
  }
  float mx = -1e30f;
#pragma unroll
  for (int e = 0; e < E_NUM; ++e) {
    float v = mk[e] ? gt[e] : -1e9f;
    if (v > mx) mx = v;
  }
  float sum = 0.0f;
  float ex[E_NUM];
#pragma unroll
  for (int e = 0; e < E_NUM; ++e) {
    ex[e] = mk[e] ? expf(gt[e] - mx) : 0.0f;
    sum += ex[e];
  }
  const float isum = 1.0f / sum;

  if (lane == 0) {
    float* lg_out = out + OUT_LOGITS + (size_t)t * E_NUM;
    float* mk_out = out + OUT_MASK + (size_t)t * E_NUM;
    float* rw = (float*)(wsb + WS_RW) + (size_t)t * E_NUM;
    unsigned mb = 0;
#pragma unroll
    for (int e = 0; e < E_NUM; ++e) {
      lg_out[e] = lg[e];
      mk_out[e] = mk[e] ? 1.0f : 0.0f;
      rw[e] = ex[e] * isum;
      if (mk[e]) mb |= (1u << e);
    }
    ((unsigned*)(wsb + WS_MASKB))[t] = mb;
  }
}

// Deterministic list build: one block per expert, prefix-scan over 8192 mask bits.
__global__ __launch_bounds__(1024) void build_lists_kernel(char* __restrict__ wsb) {
  const int e = blockIdx.x;
  const int tid = threadIdx.x;
  const unsigned* maskb = (const unsigned*)(wsb + WS_MASKB);
  const int t0 = tid * 8;
  unsigned flags = 0;
#pragma unroll
  for (int j = 0; j < 8; ++j)
    if (maskb[t0 + j] & (1u << e)) flags |= (1u << j);
  const int cnt = __popc(flags);
  const int lane = tid & 63, wid = tid >> 6;
  int v = cnt;
#pragma unroll
  for (int off = 1; off < 64; off <<= 1) {
    int u = __shfl_up(v, off);
    if (lane >= off) v += u;
  }
  __shared__ int wsum[16];
  if (lane == 63) wsum[wid] = v;
  __syncthreads();
  if (tid == 0) {
    int run = 0;
#pragma unroll
    for (int i = 0; i < 16; ++i) {
      int c = wsum[i];
      wsum[i] = run;
      run += c;
    }
    ((int*)(wsb + WS_COUNTS))[e] = run;
  }
  __syncthreads();
  int pos = wsum[wid] + v - cnt;  // exclusive prefix for this thread
  int* lists = (int*)(wsb + WS_LISTS) + e * T_TOK;
  int* posm = (int*)(wsb + WS_POS);
#pragma unroll
  for (int j = 0; j < 8; ++j) {
    const int t = t0 + j;
    int p = -1;
    if (flags & (1u << j)) {
      p = pos++;
      lists[p] = t;
    }
    posm[t * E_NUM + e] = p;
  }
}

// ---- Stage 1 (R14 verbatim): 512 thr / 8 waves, tile 256x128, K=512, fused
// ---- f32->bf16 B-transpose staging, swizzle bks^(i&7)^((i>>3)&7), + zero-fill.
__global__ __launch_bounds__(512, 4) void h_kernel(const float* __restrict__ w1,
                                                   const char* __restrict__ wsb,
                                                   unsigned short* __restrict__ hbuf,
                                                   float* __restrict__ out) {
  const int tid = threadIdx.x;
  // zero-fill chunk of full_expert_outputs (ALL blocks, incl. early-return ones)
  {
    const int bid = (blockIdx.z * 3 + blockIdx.y) * E_NUM + blockIdx.x;  // 0..767
    f32x4* full4 = (f32x4*)(out + OUT_FULL);
    const f32x4 z4 = {0.f, 0.f, 0.f, 0.f};
    const int base = bid * FILL_CHUNK;
#pragma unroll 4
    for (int i = 0; i < 43; ++i) {
      const int idx = base + i * 512 + tid;
      if (idx < FULL_F4 && idx < base + FILL_CHUNK)
        __builtin_nontemporal_store(z4, full4 + idx);
    }
  }

  const int e = blockIdx.x;
  const int ne = min(((const int*)(wsb + WS_COUNTS))[e], CAP);
  const int m0 = blockIdx.y * 256;
  if (m0 >= ne) return;
  const int i0 = blockIdx.z * 128;

  __shared__ unsigned short smem[32768];  // A [0,16384), B [16384,24576); epilogue uses all
  __shared__ int tl[256];
  const int* lists = (const int*)(wsb + WS_LISTS);
  if (tid < 256) tl[tid] = lists[e * T_TOK + min(m0 + tid, ne - 1)];
  __syncthreads();

  const unsigned short* xb = (const unsigned short*)(wsb + WS_XB);
  const unsigned short* sA[4];
  int dA[4];
#pragma unroll
  for (int it = 0; it < 4; ++it) {
    const int q = tid + it * 512, row = q >> 3, gs = q & 7;
    sA[it] = xb + (size_t)tl[row] * C_DIM + gs * 8;
    dA[it] = row * 64 + ((gs ^ (row & 7)) << 3);
  }
  const int kp = tid >> 4, kb = kp * 2, bks = kp >> 2;
  const float* wr0 = w1 + (size_t)e * C_DIM * I_DIM + (size_t)kb * I_DIM + i0;
  const int ccol = (tid & 15) * 4;

  const int lane = tid & 63, wv = tid >> 6;
  const int wm = wv >> 1, wn = wv & 1;
  const int l31 = lane & 31, kh = lane >> 5;
  f32x16 acc[2][2];
  const f32x16 zero16 = {0, 0, 0, 0, 0, 0, 0, 0, 0, 0, 0, 0, 0, 0, 0, 0};
#pragma unroll
  for (int m = 0; m < 2; ++m)
#pragma unroll
    for (int n = 0; n < 2; ++n) acc[m][n] = zero16;

  for (int ks = 0; ks < C_DIM / 64; ++ks) {
    __syncthreads();
    uint4 av[4];
#pragma unroll
    for (int it = 0; it < 4; ++it) av[it] = *(const uint4*)(sA[it] + ks * 64);
    const float* wrk = wr0 + (size_t)(ks * 64) * I_DIM;
#pragma unroll
    for (int it = 0; it < 4; ++it) *(uint4*)(smem + dA[it]) = av[it];
#pragma unroll
    for (int j = 0; j < 2; ++j) {
      const int ic = ccol + j * 64;
      const float4 v0 = *(const float4*)(wrk + ic);
      const float4 v1 = *(const float4*)(wrk + I_DIM + ic);
#pragma unroll
      for (int d = 0; d < 4; ++d) {
        const int i = ic + d;
        const unsigned pk2 = (unsigned)f2bf(((const float*)&v0)[d]) |
                             ((unsigned)f2bf(((const float*)&v1)[d]) << 16);
        *(unsigned*)(smem + 16384 + i * 64 +
                     ((bks ^ (i & 7) ^ ((i >> 3) & 7)) << 3) + (kb & 7)) = pk2;
      }
    }
    __syncthreads();
#pragma unroll
    for (int s = 0; s < 4; ++s) {
      const int sl = s * 2 + kh;
      bf16x8 af[2], bv[2];
#pragma unroll
      for (int mf = 0; mf < 2; ++mf) {
        const int r = wm * 64 + mf * 32 + l31;
        af[mf] = ldb8(smem + r * 64 + ((sl ^ (r & 7)) << 3));
      }
#pragma unroll
      for (int nf = 0; nf < 2; ++nf) {
        const int i = wn * 64 + nf * 32 + l31;
        bv[nf] = ldb8(smem + 16384 + i * 64 + ((sl ^ (i & 7) ^ ((i >> 3) & 7)) << 3));
      }
#pragma unroll
      for (int mf = 0; mf < 2; ++mf)
#pragma unroll
        for (int nf = 0; nf < 2; ++nf)
          acc[mf][nf] = __builtin_amdgcn_mfma_f32_32x32x16_bf16(af[mf], bv[nf], acc[mf][nf], 0, 0, 0);
    }
  }

  // epilogue: gelu -> bf16 pack [256][128] -> coalesced 16B stores
  __syncthreads();
#pragma unroll
  for (int mf = 0; mf < 2; ++mf)
#pragma unroll
    for (int nf = 0; nf < 2; ++nf) {
      const int col = wn * 64 + nf * 32 + l31;
#pragma unroll
      for (int r = 0; r < 16; ++r) {
        const int row = wm * 64 + mf * 32 + (r & 3) + 8 * (r >> 2) + 4 * kh;
        smem[row * 128 + col] = f2bf(gelu_f(acc[mf][nf][r]));
      }
    }
  __syncthreads();
#pragma unroll
  for (int it = 0; it < 8; ++it) {
    const int q = tid + it * 512, row = q >> 4, slot = q & 15;
    if (m0 + row < CAP)
      *(uint4*)(hbuf + (size_t)(e * CAP + m0 + row) * I_DIM + i0 + slot * 8) =
          *(const uint4*)(smem + row * 128 + slot * 8);
  }
}

// Stage 2: full[t][e][:] = H[e][pos][:] @ W2col, K=2048.
// R16: 256 thr / 4 waves, tile 128x64 -> grid 16x5x8 = 640 blocks (~2.5/CU),
// LDS 24.5KB. In-iteration loads (R14-proven), no reg prefetch.
__global__ __launch_bounds__(256, 4) void o_kernel(const float* __restrict__ w2,
                                                   const char* __restrict__ wsb,
                                                   const unsigned short* __restrict__ hbuf,
                                                   float* __restrict__ out) {
  const int e = blockIdx.x;
  const int ne = min(((const int*)(wsb + WS_COUNTS))[e], CAP);
  const int m0 = blockIdx.y * 128;
  if (m0 >= ne) return;
  const int n0 = blockIdx.z * 64;

  __shared__ unsigned short smem[12288];  // A [0,8192) = 128x64, B [8192,12288) = 64x64
  __shared__ int tl[128];
  const int tid = threadIdx.x;
  const int* lists = (const int*)(wsb + WS_LISTS);
  if (tid < 128) tl[tid] = lists[e * T_TOK + min(m0 + tid, ne - 1)];
  __syncthreads();

  const unsigned short* hb = hbuf + (size_t)e * CAP * I_DIM;
  const unsigned short* sA[4];
  int dA[4];
#pragma unroll
  for (int it = 0; it < 4; ++it) {
    const int q = tid + it * 256, row = q >> 3, gs = q & 7;
    sA[it] = hb + (size_t)(m0 + row) * I_DIM + gs * 8;
    dA[it] = row * 64 + ((gs ^ (row & 7)) << 3);
  }
  const int kp = tid >> 4, kb = kp * 2;  // kp 0..15 handles k-pairs kb and kb+32
  const float* wr0 = w2 + (size_t)e * I_DIM * C_DIM + (size_t)kb * C_DIM + n0;
  const int ccol = (tid & 15) * 4;  // 0..60 covers 64 cols

  const int lane = tid & 63, wv = tid >> 6;
  const int wm = wv >> 1, wn = wv & 1;  // wave tile 64m x 32n
  const int l31 = lane & 31, kh = lane >> 5;
  f32x16 acc[2];
  const f32x16 zero16 = {0, 0, 0, 0, 0, 0, 0, 0, 0, 0, 0, 0, 0, 0, 0, 0};
  acc[0] = zero16;
  acc[1] = zero16;

  for (int ks = 0; ks < I_DIM / 64; ++ks) {
    __syncthreads();
    uint4 av[4];
#pragma unroll
    for (int it = 0; it < 4; ++it) av[it] = *(const uint4*)(sA[it] + ks * 64);
    const float* wrk = wr0 + (size_t)(ks * 64) * C_DIM;
#pragma unroll
    for (int it = 0; it < 4; ++it) *(uint4*)(smem + dA[it]) = av[it];
#pragma unroll
    for (int j2 = 0; j2 < 2; ++j2) {
      const float* wrow = wrk + (size_t)(j2 * 32) * C_DIM;
      const int slot = (kp >> 2) + j2 * 4;
      const float4 v0 = *(const float4*)(wrow + ccol);
      const float4 v1 = *(const float4*)(wrow + C_DIM + ccol);
#pragma unroll
      for (int d = 0; d < 4; ++d) {
        const int i = ccol + d;
        const unsigned pk2 = (unsigned)f2bf(((const float*)&v0)[d]) |
                             ((unsigned)f2bf(((const float*)&v1)[d]) << 16);
        *(unsigned*)(smem + 8192 + i * 64 +
                     ((slot ^ (i & 7) ^ ((i >> 3) & 7)) << 3) + (kb & 7)) = pk2;
      }
    }
    __syncthreads();
#pragma unroll
    for (int s = 0; s < 4; ++s) {
      const int sl = s * 2 + kh;
      bf16x8 af[2], bv;
#pragma unroll
      for (int mf = 0; mf < 2; ++mf) {
        const int r = wm * 64 + mf * 32 + l31;
        af[mf] = ldb8(smem + r * 64 + ((sl ^ (r & 7)) << 3));
      }
      {
        const int i = wn * 32 + l31;
        bv = ldb8(smem + 8192 + i * 64 + ((sl ^ (i & 7) ^ ((i >> 3) & 7)) << 3));
      }
#pragma unroll
      for (int mf = 0; mf < 2; ++mf)
        acc[mf] = __builtin_amdgcn_mfma_f32_32x32x16_bf16(af[mf], bv, acc[mf], 0, 0, 0);
    }
  }

  // epilogue: plain stores into full rows
#pragma unroll
  for (int mf = 0; mf < 2; ++mf) {
    const int col = n0 + wn * 32 + l31;
#pragma unroll
    for (int r = 0; r < 16; ++r) {
      const int row = wm * 64 + mf * 32 + (r & 3) + 8 * (r >> 2) + 4 * kh;
      if (m0 + row < ne)
        out[OUT_FULL + ((size_t)tl[row] * E_NUM + e) * C_DIM + col] = acc[mf][r];
    }
  }
}

// final = sum_e rw*full over active experts (inactive rows zero-filled by h).
__global__ __launch_bounds__(256) void scatter_kernel(const char* __restrict__ wsb,
                                                      float* __restrict__ out) {
  const int tid = threadIdx.x;
  const int t = blockIdx.x * 2 + (tid >> 7);
  const int q = tid & 127;
  __shared__ float rws[2][E_NUM];
  __shared__ int ps[2][E_NUM];
  if (tid < 32) {
    const int tt = blockIdx.x * 2 + (tid >> 4);
    rws[tid >> 4][tid & 15] = ((const float*)(wsb + WS_RW))[tt * E_NUM + (tid & 15)];
    ps[tid >> 4][tid & 15] = ((const int*)(wsb + WS_POS))[tt * E_NUM + (tid & 15)];
  }
  __syncthreads();
  const int hw = tid >> 7;
  f32x4 a = {0.f, 0.f, 0.f, 0.f};
  const f32x4* full4 = (const f32x4*)(out + OUT_FULL) + (size_t)t * E_NUM * 128;
#pragma unroll 1
  for (int e = 0; e < E_NUM; ++e) {
    const int p = ps[hw][e];
    if (p >= 0 && p < CAP) {
      const float w = rws[hw][e];
      const f32x4 v = full4[e * 128 + q];
      a += w * v;
    }
  }
  __builtin_nontemporal_store(a, &((f32x4*)out)[(size_t)t * 128 + q]);
}

extern "C" void kernel_launch(void* const* d_in, const int* in_sizes, int n_in,
                              void* d_out, int out_size, void* d_ws, size_t ws_size,
                              hipStream_t stream) {
  const float* x = (const float*)d_in[0];
  const float* sim = (const float*)d_in[1];
  const float* gates = (const float*)d_in[2];
  const float* w1 = (const float*)d_in[3];
  const float* w2 = (const float*)d_in[4];
  float* out = (float*)d_out;
  char* wsb = (char*)d_ws;
  unsigned short* hbuf = (unsigned short*)(wsb + WS_H);

  hipLaunchKernelGGL(router_kernel, dim3(T_TOK / 4), dim3(256), 0, stream, x, sim, gates, wsb, out);
  hipLaunchKernelGGL(build_lists_kernel, dim3(E_NUM), dim3(1024), 0, stream, wsb);
  hipLaunchKernelGGL(h_kernel, dim3(E_NUM, 3, I_DIM / 128), dim3(512), 0, stream, w1, wsb, hbuf, out);
  hipLaunchKernelGGL(o_kernel, dim3(E_NUM, CAP / 128, C_DIM / 64), dim3(256), 0, stream,
                     w2, wsb, hbuf, out);
  hipLaunchKernelGGL(scatter_kernel, dim3(T_TOK / 2), dim3(256), 0, stream, wsb, out);
}

// Round 17
// 195.007 us; speedup vs baseline: 1.5673x; 1.0425x over previous
//
#include <hip/hip_runtime.h>
#include <hip/hip_bf16.h>
#include <math.h>

#define T_TOK 8192
#define C_DIM 512
#define I_DIM 2048
#define E_NUM 16
#define CAP 640

// ws layout (bytes); peak use ~86 MB (< proven 111 MB)
#define WS_COUNTS 0
#define WS_THR 64
#define WS_INVS 128
#define WS_RW 192
#define WS_LISTS 524480
#define WS_XB 1048768
#define WS_POS 9437376
#define WS_MASKB 9961664
#define WS_H 44040192ull /* bf16 H [E][CAP][I], 41.9 MB */

// out offsets (float elements)
#define OUT_FULL 4194304ull
#define OUT_LOGITS 71303168ull
#define OUT_MASK 71434240ull

#define FULL_F4 16777216 /* full_expert_outputs in float4 units; 2048*8192 exactly */

typedef __attribute__((ext_vector_type(8))) short bf16x8;
typedef __attribute__((ext_vector_type(4))) float f32x4;
typedef __attribute__((ext_vector_type(16))) float f32x16;

__device__ inline unsigned short f2bf(float f) {
  unsigned u = __float_as_uint(f);
  unsigned r = u + 0x7fffu + ((u >> 16) & 1u);
  return (unsigned short)(r >> 16);
}

__device__ inline bf16x8 ldb8(const unsigned short* p) {
  union { uint4 u; bf16x8 v; } w;
  w.u = *(const uint4*)p;
  return w.v;
}

__device__ inline float gelu_f(float x) {
  return 0.5f * x * (1.0f + erff(x * 0.7071067811865476f));
}

// Per-token routing; sim staged to LDS (bank-exact swizzle idx=c*17+e+(c>>3));
// thresholds + sim column norms computed per-block from the LDS copy.
// R17: also zero-fills full_expert_outputs (fire-and-forget NT stores issued
// first; they drain under this kernel's latency-bound routing work).
__global__ __launch_bounds__(256) void router_kernel(const float* __restrict__ x,
                                                     const float* __restrict__ sim,
                                                     const float* __restrict__ gates,
                                                     char* __restrict__ wsb,
                                                     float* __restrict__ out) {
  const int tid = threadIdx.x;
  // zero-fill chunk of full (2048 blocks x 8192 f32x4 = FULL_F4 exactly)
  {
    f32x4* full4 = (f32x4*)(out + OUT_FULL);
    const f32x4 z4 = {0.f, 0.f, 0.f, 0.f};
    const int base = blockIdx.x * 8192;
#pragma unroll 8
    for (int i = 0; i < 32; ++i)
      __builtin_nontemporal_store(z4, full4 + base + i * 256 + tid);
  }

  __shared__ float slds[8768];
  __shared__ float part[16][17];
  __shared__ float sthr[E_NUM], sinvs[E_NUM];
  for (int q = tid; q < C_DIM * E_NUM; q += 256)
    slds[(q >> 4) * 17 + (q & 15) + (q >> 7)] = sim[q];

  const int lane = tid & 63;
  const int t = blockIdx.x * 4 + (tid >> 6);

  const float4* xr = (const float4*)(x + (size_t)t * C_DIM + lane * 8);
  float4 v0 = xr[0], v1 = xr[1];
  float xv[8] = {v0.x, v0.y, v0.z, v0.w, v1.x, v1.y, v1.z, v1.w};

  unsigned p[4];
#pragma unroll
  for (int j = 0; j < 4; ++j)
    p[j] = (unsigned)f2bf(xv[2 * j]) | ((unsigned)f2bf(xv[2 * j + 1]) << 16);
  uint4 pk = {p[0], p[1], p[2], p[3]};
  *(uint4*)((unsigned short*)(wsb + WS_XB) + (size_t)t * C_DIM + lane * 8) = pk;

  __syncthreads();

  // per-block norms: e = tid&15, 32-c segment per thread, then 16-way reduce
  {
    const int e = tid & 15, seg = tid >> 4;
    float ps = 0.0f;
    for (int c = seg * 32; c < seg * 32 + 32; ++c) {
      const float v = slds[c * 17 + e + (c >> 3)];
      ps += v * v;
    }
    part[seg][e] = ps;
    __syncthreads();
    if (tid < E_NUM) {
      float ss = 0.0f;
#pragma unroll
      for (int s2 = 0; s2 < 16; ++s2) ss += part[s2][tid];
      sinvs[tid] = 1.0f / fmaxf(sqrtf(ss), 1e-12f);
      sthr[tid] = 1.0f / (1.0f + expf(-gates[tid]));
    }
    __syncthreads();
  }

  float ss = 0.0f;
  float acc[E_NUM];
#pragma unroll
  for (int e = 0; e < E_NUM; ++e) acc[e] = 0.0f;

  const int biL = lane * 137;  // idx(c=8*lane+j, e) = 137*lane + 17*j + e
#pragma unroll
  for (int j = 0; j < 8; ++j) {
    const float xd = xv[j];
    ss += xd * xd;
    const float* sp = slds + biL + 17 * j;
#pragma unroll
    for (int e = 0; e < E_NUM; ++e) acc[e] += xd * sp[e];
  }

#define BRED(v)                 \
  v += __shfl_xor(v, 32);       \
  v += __shfl_xor(v, 16);       \
  v += __shfl_xor(v, 8);        \
  v += __shfl_xor(v, 4);        \
  v += __shfl_xor(v, 2);        \
  v += __shfl_xor(v, 1);

  BRED(ss)
#pragma unroll
  for (int e = 0; e < E_NUM; ++e) { BRED(acc[e]) }

  const float invx = 1.0f / fmaxf(sqrtf(ss), 1e-12f);

  float lg[E_NUM], gt[E_NUM];
  bool mk[E_NUM];
  bool any = false;
#pragma unroll
  for (int e = 0; e < E_NUM; ++e) {
    lg[e] = acc[e] * invx * sinvs[e];
    float d = lg[e] - sthr[e];
    gt[e] = d > 0.0f ? d : 0.0f;
    mk[e] = d > 0.0f;
    any = any || mk[e];
  }
  if (!any) {  // fallback: one-hot argmax (first max, like np.argmax)
    int be = 0;
    float bv = lg[0];
#pragma unroll
    for (int e = 1; e < E_NUM; ++e) {
      if (lg[e] > bv) { bv = lg[e]; be = e; }
    }
#pragma unroll
    for (int e = 0; e < E_NUM; ++e) mk[e] = (e == be);
  }
  float mx = -1e30f;
#pragma unroll
  for (int e = 0; e < E_NUM; ++e) {
    float v = mk[e] ? gt[e] : -1e9f;
    if (v > mx) mx = v;
  }
  float sum = 0.0f;
  float ex[E_NUM];
#pragma unroll
  for (int e = 0; e < E_NUM; ++e) {
    ex[e] = mk[e] ? expf(gt[e] - mx) : 0.0f;
    sum += ex[e];
  }
  const float isum = 1.0f / sum;

  if (lane == 0) {
    float* lg_out = out + OUT_LOGITS + (size_t)t * E_NUM;
    float* mk_out = out + OUT_MASK + (size_t)t * E_NUM;
    float* rw = (float*)(wsb + WS_RW) + (size_t)t * E_NUM;
    unsigned mb = 0;
#pragma unroll
    for (int e = 0; e < E_NUM; ++e) {
      lg_out[e] = lg[e];
      mk_out[e] = mk[e] ? 1.0f : 0.0f;
      rw[e] = ex[e] * isum;
      if (mk[e]) mb |= (1u << e);
    }
    ((unsigned*)(wsb + WS_MASKB))[t] = mb;
  }
}

// Deterministic list build: one block per expert, prefix-scan over 8192 mask bits.
__global__ __launch_bounds__(1024) void build_lists_kernel(char* __restrict__ wsb) {
  const int e = blockIdx.x;
  const int tid = threadIdx.x;
  const unsigned* maskb = (const unsigned*)(wsb + WS_MASKB);
  const int t0 = tid * 8;
  unsigned flags = 0;
#pragma unroll
  for (int j = 0; j < 8; ++j)
    if (maskb[t0 + j] & (1u << e)) flags |= (1u << j);
  const int cnt = __popc(flags);
  const int lane = tid & 63, wid = tid >> 6;
  int v = cnt;
#pragma unroll
  for (int off = 1; off < 64; off <<= 1) {
    int u = __shfl_up(v, off);
    if (lane >= off) v += u;
  }
  __shared__ int wsum[16];
  if (lane == 63) wsum[wid] = v;
  __syncthreads();
  if (tid == 0) {
    int run = 0;
#pragma unroll
    for (int i = 0; i < 16; ++i) {
      int c = wsum[i];
      wsum[i] = run;
      run += c;
    }
    ((int*)(wsb + WS_COUNTS))[e] = run;
  }
  __syncthreads();
  int pos = wsum[wid] + v - cnt;  // exclusive prefix for this thread
  int* lists = (int*)(wsb + WS_LISTS) + e * T_TOK;
  int* posm = (int*)(wsb + WS_POS);
#pragma unroll
  for (int j = 0; j < 8; ++j) {
    const int t = t0 + j;
    int p = -1;
    if (flags & (1u << j)) {
      p = pos++;
      lists[p] = t;
    }
    posm[t * E_NUM + e] = p;
  }
}

// ---- Stage 1: 512 thr / 8 waves, tile 256x128, K=512, fused f32->bf16
// ---- B-transpose staging, swizzle bks^(i&7)^((i>>3)&7). (fill moved to router)
__global__ __launch_bounds__(512, 4) void h_kernel(const float* __restrict__ w1,
                                                   const char* __restrict__ wsb,
                                                   unsigned short* __restrict__ hbuf) {
  const int tid = threadIdx.x;
  const int e = blockIdx.x;
  const int ne = min(((const int*)(wsb + WS_COUNTS))[e], CAP);
  const int m0 = blockIdx.y * 256;
  if (m0 >= ne) return;
  const int i0 = blockIdx.z * 128;

  __shared__ unsigned short smem[32768];  // A [0,16384), B [16384,24576); epilogue uses all
  __shared__ int tl[256];
  const int* lists = (const int*)(wsb + WS_LISTS);
  if (tid < 256) tl[tid] = lists[e * T_TOK + min(m0 + tid, ne - 1)];
  __syncthreads();

  const unsigned short* xb = (const unsigned short*)(wsb + WS_XB);
  const unsigned short* sA[4];
  int dA[4];
#pragma unroll
  for (int it = 0; it < 4; ++it) {
    const int q = tid + it * 512, row = q >> 3, gs = q & 7;
    sA[it] = xb + (size_t)tl[row] * C_DIM + gs * 8;
    dA[it] = row * 64 + ((gs ^ (row & 7)) << 3);
  }
  const int kp = tid >> 4, kb = kp * 2, bks = kp >> 2;
  const float* wr0 = w1 + (size_t)e * C_DIM * I_DIM + (size_t)kb * I_DIM + i0;
  const int ccol = (tid & 15) * 4;

  const int lane = tid & 63, wv = tid >> 6;
  const int wm = wv >> 1, wn = wv & 1;
  const int l31 = lane & 31, kh = lane >> 5;
  f32x16 acc[2][2];
  const f32x16 zero16 = {0, 0, 0, 0, 0, 0, 0, 0, 0, 0, 0, 0, 0, 0, 0, 0};
#pragma unroll
  for (int m = 0; m < 2; ++m)
#pragma unroll
    for (int n = 0; n < 2; ++n) acc[m][n] = zero16;

  for (int ks = 0; ks < C_DIM / 64; ++ks) {
    __syncthreads();
    uint4 av[4];
#pragma unroll
    for (int it = 0; it < 4; ++it) av[it] = *(const uint4*)(sA[it] + ks * 64);
    const float* wrk = wr0 + (size_t)(ks * 64) * I_DIM;
#pragma unroll
    for (int it = 0; it < 4; ++it) *(uint4*)(smem + dA[it]) = av[it];
#pragma unroll
    for (int j = 0; j < 2; ++j) {
      const int ic = ccol + j * 64;
      const float4 v0 = *(const float4*)(wrk + ic);
      const float4 v1 = *(const float4*)(wrk + I_DIM + ic);
#pragma unroll
      for (int d = 0; d < 4; ++d) {
        const int i = ic + d;
        const unsigned pk2 = (unsigned)f2bf(((const float*)&v0)[d]) |
                             ((unsigned)f2bf(((const float*)&v1)[d]) << 16);
        *(unsigned*)(smem + 16384 + i * 64 +
                     ((bks ^ (i & 7) ^ ((i >> 3) & 7)) << 3) + (kb & 7)) = pk2;
      }
    }
    __syncthreads();
#pragma unroll
    for (int s = 0; s < 4; ++s) {
      const int sl = s * 2 + kh;
      bf16x8 af[2], bv[2];
#pragma unroll
      for (int mf = 0; mf < 2; ++mf) {
        const int r = wm * 64 + mf * 32 + l31;
        af[mf] = ldb8(smem + r * 64 + ((sl ^ (r & 7)) << 3));
      }
#pragma unroll
      for (int nf = 0; nf < 2; ++nf) {
        const int i = wn * 64 + nf * 32 + l31;
        bv[nf] = ldb8(smem + 16384 + i * 64 + ((sl ^ (i & 7) ^ ((i >> 3) & 7)) << 3));
      }
#pragma unroll
      for (int mf = 0; mf < 2; ++mf)
#pragma unroll
        for (int nf = 0; nf < 2; ++nf)
          acc[mf][nf] = __builtin_amdgcn_mfma_f32_32x32x16_bf16(af[mf], bv[nf], acc[mf][nf], 0, 0, 0);
    }
  }

  // epilogue: gelu -> bf16 pack [256][128] -> coalesced 16B stores
  __syncthreads();
#pragma unroll
  for (int mf = 0; mf < 2; ++mf)
#pragma unroll
    for (int nf = 0; nf < 2; ++nf) {
      const int col = wn * 64 + nf * 32 + l31;
#pragma unroll
      for (int r = 0; r < 16; ++r) {
        const int row = wm * 64 + mf * 32 + (r & 3) + 8 * (r >> 2) + 4 * kh;
        smem[row * 128 + col] = f2bf(gelu_f(acc[mf][nf][r]));
      }
    }
  __syncthreads();
#pragma unroll
  for (int it = 0; it < 8; ++it) {
    const int q = tid + it * 512, row = q >> 4, slot = q & 15;
    if (m0 + row < CAP)
      *(uint4*)(hbuf + (size_t)(e * CAP + m0 + row) * I_DIM + i0 + slot * 8) =
          *(const uint4*)(smem + row * 128 + slot * 8);
  }
}

// Stage 2: full[t][e][:] = H[e][pos][:] @ W2col, K=2048.
// 256 thr / 4 waves, tile 128x64 -> grid 16x5x8 = 640 blocks (~2.5/CU).
__global__ __launch_bounds__(256, 4) void o_kernel(const float* __restrict__ w2,
                                                   const char* __restrict__ wsb,
                                                   const unsigned short* __restrict__ hbuf,
                                                   float* __restrict__ out) {
  const int e = blockIdx.x;
  const int ne = min(((const int*)(wsb + WS_COUNTS))[e], CAP);
  const int m0 = blockIdx.y * 128;
  if (m0 >= ne) return;
  const int n0 = blockIdx.z * 64;

  __shared__ unsigned short smem[12288];  // A [0,8192) = 128x64, B [8192,12288) = 64x64
  __shared__ int tl[128];
  const int tid = threadIdx.x;
  const int* lists = (const int*)(wsb + WS_LISTS);
  if (tid < 128) tl[tid] = lists[e * T_TOK + min(m0 + tid, ne - 1)];
  __syncthreads();

  const unsigned short* hb = hbuf + (size_t)e * CAP * I_DIM;
  const unsigned short* sA[4];
  int dA[4];
#pragma unroll
  for (int it = 0; it < 4; ++it) {
    const int q = tid + it * 256, row = q >> 3, gs = q & 7;
    sA[it] = hb + (size_t)(m0 + row) * I_DIM + gs * 8;
    dA[it] = row * 64 + ((gs ^ (row & 7)) << 3);
  }
  const int kp = tid >> 4, kb = kp * 2;
  const float* wr0 = w2 + (size_t)e * I_DIM * C_DIM + (size_t)kb * C_DIM + n0;
  const int ccol = (tid & 15) * 4;  // 0..60 covers 64 cols

  const int lane = tid & 63, wv = tid >> 6;
  const int wm = wv >> 1, wn = wv & 1;  // wave tile 64m x 32n
  const int l31 = lane & 31, kh = lane >> 5;
  f32x16 acc[2];
  const f32x16 zero16 = {0, 0, 0, 0, 0, 0, 0, 0, 0, 0, 0, 0, 0, 0, 0, 0};
  acc[0] = zero16;
  acc[1] = zero16;

  for (int ks = 0; ks < I_DIM / 64; ++ks) {
    __syncthreads();
    uint4 av[4];
#pragma unroll
    for (int it = 0; it < 4; ++it) av[it] = *(const uint4*)(sA[it] + ks * 64);
    const float* wrk = wr0 + (size_t)(ks * 64) * C_DIM;
#pragma unroll
    for (int it = 0; it < 4; ++it) *(uint4*)(smem + dA[it]) = av[it];
#pragma unroll
    for (int j2 = 0; j2 < 2; ++j2) {
      const float* wrow = wrk + (size_t)(j2 * 32) * C_DIM;
      const int slot = (kp >> 2) + j2 * 4;
      const float4 v0 = *(const float4*)(wrow + ccol);
      const float4 v1 = *(const float4*)(wrow + C_DIM + ccol);
#pragma unroll
      for (int d = 0; d < 4; ++d) {
        const int i = ccol + d;
        const unsigned pk2 = (unsigned)f2bf(((const float*)&v0)[d]) |
                             ((unsigned)f2bf(((const float*)&v1)[d]) << 16);
        *(unsigned*)(smem + 8192 + i * 64 +
                     ((slot ^ (i & 7) ^ ((i >> 3) & 7)) << 3) + (kb & 7)) = pk2;
      }
    }
    __syncthreads();
#pragma unroll
    for (int s = 0; s < 4; ++s) {
      const int sl = s * 2 + kh;
      bf16x8 af[2], bv;
#pragma unroll
      for (int mf = 0; mf < 2; ++mf) {
        const int r = wm * 64 + mf * 32 + l31;
        af[mf] = ldb8(smem + r * 64 + ((sl ^ (r & 7)) << 3));
      }
      {
        const int i = wn * 32 + l31;
        bv = ldb8(smem + 8192 + i * 64 + ((sl ^ (i & 7) ^ ((i >> 3) & 7)) << 3));
      }
#pragma unroll
      for (int mf = 0; mf < 2; ++mf)
        acc[mf] = __builtin_amdgcn_mfma_f32_32x32x16_bf16(af[mf], bv, acc[mf], 0, 0, 0);
    }
  }

  // epilogue: plain stores into full rows
#pragma unroll
  for (int mf = 0; mf < 2; ++mf) {
    const int col = n0 + wn * 32 + l31;
#pragma unroll
    for (int r = 0; r < 16; ++r) {
      const int row = wm * 64 + mf * 32 + (r & 3) + 8 * (r >> 2) + 4 * kh;
      if (m0 + row < ne)
        out[OUT_FULL + ((size_t)tl[row] * E_NUM + e) * C_DIM + col] = acc[mf][r];
    }
  }
}

// final = sum_e rw*full over active experts (inactive rows zero-filled by router).
__global__ __launch_bounds__(256) void scatter_kernel(const char* __restrict__ wsb,
                                                      float* __restrict__ out) {
  const int tid = threadIdx.x;
  const int t = blockIdx.x * 2 + (tid >> 7);
  const int q = tid & 127;
  __shared__ float rws[2][E_NUM];
  __shared__ int ps[2][E_NUM];
  if (tid < 32) {
    const int tt = blockIdx.x * 2 + (tid >> 4);
    rws[tid >> 4][tid & 15] = ((const float*)(wsb + WS_RW))[tt * E_NUM + (tid & 15)];
    ps[tid >> 4][tid & 15] = ((const int*)(wsb + WS_POS))[tt * E_NUM + (tid & 15)];
  }
  __syncthreads();
  const int hw = tid >> 7;
  f32x4 a = {0.f, 0.f, 0.f, 0.f};
  const f32x4* full4 = (const f32x4*)(out + OUT_FULL) + (size_t)t * E_NUM * 128;
#pragma unroll 1
  for (int e = 0; e < E_NUM; ++e) {
    const int p = ps[hw][e];
    if (p >= 0 && p < CAP) {
      const float w = rws[hw][e];
      const f32x4 v = full4[e * 128 + q];
      a += w * v;
    }
  }
  __builtin_nontemporal_store(a, &((f32x4*)out)[(size_t)t * 128 + q]);
}

extern "C" void kernel_launch(void* const* d_in, const int* in_sizes, int n_in,
                              void* d_out, int out_size, void* d_ws, size_t ws_size,
                              hipStream_t stream) {
  const float* x = (const float*)d_in[0];
  const float* sim = (const float*)d_in[1];
  const float* gates = (const float*)d_in[2];
  const float* w1 = (const float*)d_in[3];
  const float* w2 = (const float*)d_in[4];
  float* out = (float*)d_out;
  char* wsb = (char*)d_ws;
  unsigned short* hbuf = (unsigned short*)(wsb + WS_H);

  hipLaunchKernelGGL(router_kernel, dim3(T_TOK / 4), dim3(256), 0, stream, x, sim, gates, wsb, out);
  hipLaunchKernelGGL(build_lists_kernel, dim3(E_NUM), dim3(1024), 0, stream, wsb);
  hipLaunchKernelGGL(h_kernel, dim3(E_NUM, 3, I_DIM / 128), dim3(512), 0, stream, w1, wsb, hbuf);
  hipLaunchKernelGGL(o_kernel, dim3(E_NUM, CAP / 128, C_DIM / 64), dim3(256), 0, stream,
                     w2, wsb, hbuf, out);
  hipLaunchKernelGGL(scatter_kernel, dim3(T_TOK / 2), dim3(256), 0, stream, wsb, out);
}

// Round 18
// 193.943 us; speedup vs baseline: 1.5759x; 1.0055x over previous
//
#include <hip/hip_runtime.h>
#include <hip/hip_bf16.h>
#include <math.h>

#define T_TOK 8192
#define C_DIM 512
#define I_DIM 2048
#define E_NUM 16
#define CAP 640

// ws layout (bytes); peak use ~86 MB (< proven 111 MB)
#define WS_COUNTS 0
#define WS_THR 64
#define WS_INVS 128
#define WS_RW 192
#define WS_LISTS 524480
#define WS_XB 1048768
#define WS_POS 9437376
#define WS_MASKB 9961664
#define WS_H 44040192ull /* bf16 H [E][CAP][I], 41.9 MB */

// out offsets (float elements)
#define OUT_FULL 4194304ull
#define OUT_LOGITS 71303168ull
#define OUT_MASK 71434240ull

#define FULL_F4 16777216 /* full_expert_outputs in float4 units; 2048*8192 exactly */

typedef __attribute__((ext_vector_type(8))) short bf16x8;
typedef __attribute__((ext_vector_type(4))) float f32x4;
typedef __attribute__((ext_vector_type(16))) float f32x16;

__device__ inline unsigned short f2bf(float f) {
  unsigned u = __float_as_uint(f);
  unsigned r = u + 0x7fffu + ((u >> 16) & 1u);
  return (unsigned short)(r >> 16);
}

__device__ inline bf16x8 ldb8(const unsigned short* p) {
  union { uint4 u; bf16x8 v; } w;
  w.u = *(const uint4*)p;
  return w.v;
}

__device__ inline float gelu_f(float x) {
  return 0.5f * x * (1.0f + erff(x * 0.7071067811865476f));
}

// Per-token routing; sim staged to LDS (bank-exact swizzle idx=c*17+e+(c>>3));
// thresholds + sim column norms computed per-block from the LDS copy.
// Also zero-fills full_expert_outputs (fire-and-forget NT stores issued first;
// they drain under this kernel's latency-bound routing work).
__global__ __launch_bounds__(256) void router_kernel(const float* __restrict__ x,
                                                     const float* __restrict__ sim,
                                                     const float* __restrict__ gates,
                                                     char* __restrict__ wsb,
                                                     float* __restrict__ out) {
  const int tid = threadIdx.x;
  // zero-fill chunk of full (2048 blocks x 8192 f32x4 = FULL_F4 exactly)
  {
    f32x4* full4 = (f32x4*)(out + OUT_FULL);
    const f32x4 z4 = {0.f, 0.f, 0.f, 0.f};
    const int base = blockIdx.x * 8192;
#pragma unroll 8
    for (int i = 0; i < 32; ++i)
      __builtin_nontemporal_store(z4, full4 + base + i * 256 + tid);
  }

  __shared__ float slds[8768];
  __shared__ float part[16][17];
  __shared__ float sthr[E_NUM], sinvs[E_NUM];
  for (int q = tid; q < C_DIM * E_NUM; q += 256)
    slds[(q >> 4) * 17 + (q & 15) + (q >> 7)] = sim[q];

  const int lane = tid & 63;
  const int t = blockIdx.x * 4 + (tid >> 6);

  const float4* xr = (const float4*)(x + (size_t)t * C_DIM + lane * 8);
  float4 v0 = xr[0], v1 = xr[1];
  float xv[8] = {v0.x, v0.y, v0.z, v0.w, v1.x, v1.y, v1.z, v1.w};

  unsigned p[4];
#pragma unroll
  for (int j = 0; j < 4; ++j)
    p[j] = (unsigned)f2bf(xv[2 * j]) | ((unsigned)f2bf(xv[2 * j + 1]) << 16);
  uint4 pk = {p[0], p[1], p[2], p[3]};
  *(uint4*)((unsigned short*)(wsb + WS_XB) + (size_t)t * C_DIM + lane * 8) = pk;

  __syncthreads();

  // per-block norms: e = tid&15, 32-c segment per thread, then 16-way reduce
  {
    const int e = tid & 15, seg = tid >> 4;
    float ps = 0.0f;
    for (int c = seg * 32; c < seg * 32 + 32; ++c) {
      const float v = slds[c * 17 + e + (c >> 3)];
      ps += v * v;
    }
    part[seg][e] = ps;
    __syncthreads();
    if (tid < E_NUM) {
      float ss = 0.0f;
#pragma unroll
      for (int s2 = 0; s2 < 16; ++s2) ss += part[s2][tid];
      sinvs[tid] = 1.0f / fmaxf(sqrtf(ss), 1e-12f);
      sthr[tid] = 1.0f / (1.0f + expf(-gates[tid]));
    }
    __syncthreads();
  }

  float ss = 0.0f;
  float acc[E_NUM];
#pragma unroll
  for (int e = 0; e < E_NUM; ++e) acc[e] = 0.0f;

  const int biL = lane * 137;  // idx(c=8*lane+j, e) = 137*lane + 17*j + e
#pragma unroll
  for (int j = 0; j < 8; ++j) {
    const float xd = xv[j];
    ss += xd * xd;
    const float* sp = slds + biL + 17 * j;
#pragma unroll
    for (int e = 0; e < E_NUM; ++e) acc[e] += xd * sp[e];
  }

#define BRED(v)                 \
  v += __shfl_xor(v, 32);       \
  v += __shfl_xor(v, 16);       \
  v += __shfl_xor(v, 8);        \
  v += __shfl_xor(v, 4);        \
  v += __shfl_xor(v, 2);        \
  v += __shfl_xor(v, 1);

  BRED(ss)
#pragma unroll
  for (int e = 0; e < E_NUM; ++e) { BRED(acc[e]) }

  const float invx = 1.0f / fmaxf(sqrtf(ss), 1e-12f);

  float lg[E_NUM], gt[E_NUM];
  bool mk[E_NUM];
  bool any = false;
#pragma unroll
  for (int e = 0; e < E_NUM; ++e) {
    lg[e] = acc[e] * invx * sinvs[e];
    float d = lg[e] - sthr[e];
    gt[e] = d > 0.0f ? d : 0.0f;
    mk[e] = d > 0.0f;
    any = any || mk[e];
  }
  if (!any) {  // fallback: one-hot argmax (first max, like np.argmax)
    int be = 0;
    float bv = lg[0];
#pragma unroll
    for (int e = 1; e < E_NUM; ++e) {
      if (lg[e] > bv) { bv = lg[e]; be = e; }
    }
#pragma unroll
    for (int e = 0; e < E_NUM; ++e) mk[e] = (e == be);
  }
  float mx = -1e30f;
#pragma unroll
  for (int e = 0; e < E_NUM; ++e) {
    float v = mk[e] ? gt[e] : -1e9f;
    if (v > mx) mx = v;
  }
  float sum = 0.0f;
  float ex[E_NUM];
#pragma unroll
  for (int e = 0; e < E_NUM; ++e) {
    ex[e] = mk[e] ? expf(gt[e] - mx) : 0.0f;
    sum += ex[e];
  }
  const float isum = 1.0f / sum;

  if (lane == 0) {
    float* lg_out = out + OUT_LOGITS + (size_t)t * E_NUM;
    float* mk_out = out + OUT_MASK + (size_t)t * E_NUM;
    float* rw = (float*)(wsb + WS_RW) + (size_t)t * E_NUM;
    unsigned mb = 0;
#pragma unroll
    for (int e = 0; e < E_NUM; ++e) {
      lg_out[e] = lg[e];
      mk_out[e] = mk[e] ? 1.0f : 0.0f;
      rw[e] = ex[e] * isum;
      if (mk[e]) mb |= (1u << e);
    }
    ((unsigned*)(wsb + WS_MASKB))[t] = mb;
  }
}

// Deterministic list build: one block per expert, prefix-scan over 8192 mask bits.
__global__ __launch_bounds__(1024) void build_lists_kernel(char* __restrict__ wsb) {
  const int e = blockIdx.x;
  const int tid = threadIdx.x;
  const unsigned* maskb = (const unsigned*)(wsb + WS_MASKB);
  const int t0 = tid * 8;
  unsigned flags = 0;
#pragma unroll
  for (int j = 0; j < 8; ++j)
    if (maskb[t0 + j] & (1u << e)) flags |= (1u << j);
  const int cnt = __popc(flags);
  const int lane = tid & 63, wid = tid >> 6;
  int v = cnt;
#pragma unroll
  for (int off = 1; off < 64; off <<= 1) {
    int u = __shfl_up(v, off);
    if (lane >= off) v += u;
  }
  __shared__ int wsum[16];
  if (lane == 63) wsum[wid] = v;
  __syncthreads();
  if (tid == 0) {
    int run = 0;
#pragma unroll
    for (int i = 0; i < 16; ++i) {
      int c = wsum[i];
      wsum[i] = run;
      run += c;
    }
    ((int*)(wsb + WS_COUNTS))[e] = run;
  }
  __syncthreads();
  int pos = wsum[wid] + v - cnt;  // exclusive prefix for this thread
  int* lists = (int*)(wsb + WS_LISTS) + e * T_TOK;
  int* posm = (int*)(wsb + WS_POS);
#pragma unroll
  for (int j = 0; j < 8; ++j) {
    const int t = t0 + j;
    int p = -1;
    if (flags & (1u << j)) {
      p = pos++;
      lists[p] = t;
    }
    posm[t * E_NUM + e] = p;
  }
}

// ---- Stage 1: 512 thr / 8 waves, tile 256x128, K=512, fused f32->bf16
// ---- B-transpose staging, swizzle bks^(i&7)^((i>>3)&7).
__global__ __launch_bounds__(512, 4) void h_kernel(const float* __restrict__ w1,
                                                   const char* __restrict__ wsb,
                                                   unsigned short* __restrict__ hbuf) {
  const int tid = threadIdx.x;
  const int e = blockIdx.x;
  const int ne = min(((const int*)(wsb + WS_COUNTS))[e], CAP);
  const int m0 = blockIdx.y * 256;
  if (m0 >= ne) return;
  const int i0 = blockIdx.z * 128;

  __shared__ unsigned short smem[32768];  // A [0,16384), B [16384,24576); epilogue uses all
  __shared__ int tl[256];
  const int* lists = (const int*)(wsb + WS_LISTS);
  if (tid < 256) tl[tid] = lists[e * T_TOK + min(m0 + tid, ne - 1)];
  __syncthreads();

  const unsigned short* xb = (const unsigned short*)(wsb + WS_XB);
  const unsigned short* sA[4];
  int dA[4];
#pragma unroll
  for (int it = 0; it < 4; ++it) {
    const int q = tid + it * 512, row = q >> 3, gs = q & 7;
    sA[it] = xb + (size_t)tl[row] * C_DIM + gs * 8;
    dA[it] = row * 64 + ((gs ^ (row & 7)) << 3);
  }
  const int kp = tid >> 4, kb = kp * 2, bks = kp >> 2;
  const float* wr0 = w1 + (size_t)e * C_DIM * I_DIM + (size_t)kb * I_DIM + i0;
  const int ccol = (tid & 15) * 4;

  const int lane = tid & 63, wv = tid >> 6;
  const int wm = wv >> 1, wn = wv & 1;
  const int l31 = lane & 31, kh = lane >> 5;
  f32x16 acc[2][2];
  const f32x16 zero16 = {0, 0, 0, 0, 0, 0, 0, 0, 0, 0, 0, 0, 0, 0, 0, 0};
#pragma unroll
  for (int m = 0; m < 2; ++m)
#pragma unroll
    for (int n = 0; n < 2; ++n) acc[m][n] = zero16;

  for (int ks = 0; ks < C_DIM / 64; ++ks) {
    __syncthreads();
    uint4 av[4];
#pragma unroll
    for (int it = 0; it < 4; ++it) av[it] = *(const uint4*)(sA[it] + ks * 64);
    const float* wrk = wr0 + (size_t)(ks * 64) * I_DIM;
#pragma unroll
    for (int it = 0; it < 4; ++it) *(uint4*)(smem + dA[it]) = av[it];
#pragma unroll
    for (int j = 0; j < 2; ++j) {
      const int ic = ccol + j * 64;
      const float4 v0 = *(const float4*)(wrk + ic);
      const float4 v1 = *(const float4*)(wrk + I_DIM + ic);
#pragma unroll
      for (int d = 0; d < 4; ++d) {
        const int i = ic + d;
        const unsigned pk2 = (unsigned)f2bf(((const float*)&v0)[d]) |
                             ((unsigned)f2bf(((const float*)&v1)[d]) << 16);
        *(unsigned*)(smem + 16384 + i * 64 +
                     ((bks ^ (i & 7) ^ ((i >> 3) & 7)) << 3) + (kb & 7)) = pk2;
      }
    }
    __syncthreads();
#pragma unroll
    for (int s = 0; s < 4; ++s) {
      const int sl = s * 2 + kh;
      bf16x8 af[2], bv[2];
#pragma unroll
      for (int mf = 0; mf < 2; ++mf) {
        const int r = wm * 64 + mf * 32 + l31;
        af[mf] = ldb8(smem + r * 64 + ((sl ^ (r & 7)) << 3));
      }
#pragma unroll
      for (int nf = 0; nf < 2; ++nf) {
        const int i = wn * 64 + nf * 32 + l31;
        bv[nf] = ldb8(smem + 16384 + i * 64 + ((sl ^ (i & 7) ^ ((i >> 3) & 7)) << 3));
      }
#pragma unroll
      for (int mf = 0; mf < 2; ++mf)
#pragma unroll
        for (int nf = 0; nf < 2; ++nf)
          acc[mf][nf] = __builtin_amdgcn_mfma_f32_32x32x16_bf16(af[mf], bv[nf], acc[mf][nf], 0, 0, 0);
    }
  }

  // epilogue: gelu -> bf16 pack [256][128] -> coalesced 16B stores
  __syncthreads();
#pragma unroll
  for (int mf = 0; mf < 2; ++mf)
#pragma unroll
    for (int nf = 0; nf < 2; ++nf) {
      const int col = wn * 64 + nf * 32 + l31;
#pragma unroll
      for (int r = 0; r < 16; ++r) {
        const int row = wm * 64 + mf * 32 + (r & 3) + 8 * (r >> 2) + 4 * kh;
        smem[row * 128 + col] = f2bf(gelu_f(acc[mf][nf][r]));
      }
    }
  __syncthreads();
#pragma unroll
  for (int it = 0; it < 8; ++it) {
    const int q = tid + it * 512, row = q >> 4, slot = q & 15;
    if (m0 + row < CAP)
      *(uint4*)(hbuf + (size_t)(e * CAP + m0 + row) * I_DIM + i0 + slot * 8) =
          *(const uint4*)(smem + row * 128 + slot * 8);
  }
}

// Stage 2: full[t][e][:] = H[e][pos][:] @ W2col, K=2048.
// 256 thr / 4 waves, tile 128x64, grid 16x5x8 = 640 blocks.
// R18: LDS double-buffer, ONE barrier per K-step (stage(k+1) || compute(k)).
__global__ __launch_bounds__(256, 4) void o_kernel(const float* __restrict__ w2,
                                                   const char* __restrict__ wsb,
                                                   const unsigned short* __restrict__ hbuf,
                                                   float* __restrict__ out) {
  const int e = blockIdx.x;
  const int ne = min(((const int*)(wsb + WS_COUNTS))[e], CAP);
  const int m0 = blockIdx.y * 128;
  if (m0 >= ne) return;
  const int n0 = blockIdx.z * 64;

  __shared__ unsigned short smem[24576];  // dbuf: half = 12288 (A [0,8192), B [8192,12288))
  __shared__ int tl[128];
  const int tid = threadIdx.x;
  const int* lists = (const int*)(wsb + WS_LISTS);
  if (tid < 128) tl[tid] = lists[e * T_TOK + min(m0 + tid, ne - 1)];
  __syncthreads();

  const unsigned short* hb = hbuf + (size_t)e * CAP * I_DIM;
  const unsigned short* sA[4];
  int dA[4];
#pragma unroll
  for (int it = 0; it < 4; ++it) {
    const int q = tid + it * 256, row = q >> 3, gs = q & 7;
    sA[it] = hb + (size_t)(m0 + row) * I_DIM + gs * 8;
    dA[it] = row * 64 + ((gs ^ (row & 7)) << 3);
  }
  const int kp = tid >> 4, kb = kp * 2;
  const float* wr0 = w2 + (size_t)e * I_DIM * C_DIM + (size_t)kb * C_DIM + n0;
  const int ccol = (tid & 15) * 4;  // 0..60 covers 64 cols

  const int lane = tid & 63, wv = tid >> 6;
  const int wm = wv >> 1, wn = wv & 1;  // wave tile 64m x 32n
  const int l31 = lane & 31, kh = lane >> 5;
  f32x16 acc[2];
  const f32x16 zero16 = {0, 0, 0, 0, 0, 0, 0, 0, 0, 0, 0, 0, 0, 0, 0, 0};
  acc[0] = zero16;
  acc[1] = zero16;

  auto stage = [&](int ks) {
    unsigned short* sb = smem + (ks & 1) * 12288;
    uint4 av[4];
#pragma unroll
    for (int it = 0; it < 4; ++it) av[it] = *(const uint4*)(sA[it] + ks * 64);
    const float* wrk = wr0 + (size_t)(ks * 64) * C_DIM;
#pragma unroll
    for (int it = 0; it < 4; ++it) *(uint4*)(sb + dA[it]) = av[it];
#pragma unroll
    for (int j2 = 0; j2 < 2; ++j2) {
      const float* wrow = wrk + (size_t)(j2 * 32) * C_DIM;
      const int slot = (kp >> 2) + j2 * 4;
      const float4 v0 = *(const float4*)(wrow + ccol);
      const float4 v1 = *(const float4*)(wrow + C_DIM + ccol);
#pragma unroll
      for (int d = 0; d < 4; ++d) {
        const int i = ccol + d;
        const unsigned pk2 = (unsigned)f2bf(((const float*)&v0)[d]) |
                             ((unsigned)f2bf(((const float*)&v1)[d]) << 16);
        *(unsigned*)(sb + 8192 + i * 64 +
                     ((slot ^ (i & 7) ^ ((i >> 3) & 7)) << 3) + (kb & 7)) = pk2;
      }
    }
  };

  stage(0);
  for (int ks = 0; ks < I_DIM / 64; ++ks) {
    __syncthreads();  // stage(ks) writes visible; compute(ks-1) reads drained
    if (ks + 1 < I_DIM / 64) stage(ks + 1);
    const unsigned short* sb = smem + (ks & 1) * 12288;
#pragma unroll
    for (int s = 0; s < 4; ++s) {
      const int sl = s * 2 + kh;
      bf16x8 af[2], bv;
#pragma unroll
      for (int mf = 0; mf < 2; ++mf) {
        const int r = wm * 64 + mf * 32 + l31;
        af[mf] = ldb8(sb + r * 64 + ((sl ^ (r & 7)) << 3));
      }
      {
        const int i = wn * 32 + l31;
        bv = ldb8(sb + 8192 + i * 64 + ((sl ^ (i & 7) ^ ((i >> 3) & 7)) << 3));
      }
#pragma unroll
      for (int mf = 0; mf < 2; ++mf)
        acc[mf] = __builtin_amdgcn_mfma_f32_32x32x16_bf16(af[mf], bv, acc[mf], 0, 0, 0);
    }
  }

  // epilogue: plain stores into full rows
#pragma unroll
  for (int mf = 0; mf < 2; ++mf) {
    const int col = n0 + wn * 32 + l31;
#pragma unroll
    for (int r = 0; r < 16; ++r) {
      const int row = wm * 64 + mf * 32 + (r & 3) + 8 * (r >> 2) + 4 * kh;
      if (m0 + row < ne)
        out[OUT_FULL + ((size_t)tl[row] * E_NUM + e) * C_DIM + col] = acc[mf][r];
    }
  }
}

// final = sum_e rw*full over active experts (inactive rows zero-filled by router).
__global__ __launch_bounds__(256) void scatter_kernel(const char* __restrict__ wsb,
                                                      float* __restrict__ out) {
  const int tid = threadIdx.x;
  const int t = blockIdx.x * 2 + (tid >> 7);
  const int q = tid & 127;
  __shared__ float rws[2][E_NUM];
  __shared__ int ps[2][E_NUM];
  if (tid < 32) {
    const int tt = blockIdx.x * 2 + (tid >> 4);
    rws[tid >> 4][tid & 15] = ((const float*)(wsb + WS_RW))[tt * E_NUM + (tid & 15)];
    ps[tid >> 4][tid & 15] = ((const int*)(wsb + WS_POS))[tt * E_NUM + (tid & 15)];
  }
  __syncthreads();
  const int hw = tid >> 7;
  f32x4 a = {0.f, 0.f, 0.f, 0.f};
  const f32x4* full4 = (const f32x4*)(out + OUT_FULL) + (size_t)t * E_NUM * 128;
#pragma unroll 1
  for (int e = 0; e < E_NUM; ++e) {
    const int p = ps[hw][e];
    if (p >= 0 && p < CAP) {
      const float w = rws[hw][e];
      const f32x4 v = full4[e * 128 + q];
      a += w * v;
    }
  }
  __builtin_nontemporal_store(a, &((f32x4*)out)[(size_t)t * 128 + q]);
}

extern "C" void kernel_launch(void* const* d_in, const int* in_sizes, int n_in,
                              void* d_out, int out_size, void* d_ws, size_t ws_size,
                              hipStream_t stream) {
  const float* x = (const float*)d_in[0];
  const float* sim = (const float*)d_in[1];
  const float* gates = (const float*)d_in[2];
  const float* w1 = (const float*)d_in[3];
  const float* w2 = (const float*)d_in[4];
  float* out = (float*)d_out;
  char* wsb = (char*)d_ws;
  unsigned short* hbuf = (unsigned short*)(wsb + WS_H);

  hipLaunchKernelGGL(router_kernel, dim3(T_TOK / 4), dim3(256), 0, stream, x, sim, gates, wsb, out);
  hipLaunchKernelGGL(build_lists_kernel, dim3(E_NUM), dim3(1024), 0, stream, wsb);
  hipLaunchKernelGGL(h_kernel, dim3(E_NUM, 3, I_DIM / 128), dim3(512), 0, stream, w1, wsb, hbuf);
  hipLaunchKernelGGL(o_kernel, dim3(E_NUM, CAP / 128, C_DIM / 64), dim3(256), 0, stream,
                     w2, wsb, hbuf, out);
  hipLaunchKernelGGL(scatter_kernel, dim3(T_TOK / 2), dim3(256), 0, stream, wsb, out);
}